// Round 4
// baseline (237.430 us; speedup 1.0000x reference)
//
#include <hip/hip_runtime.h>
#include <math.h>

// GCN 2-layer forward on MI355X.
// Lessons r2-r6: (a) random 4B global stores => ~130MB writebacks however
// sharded; (b) coarse buckets => 32x re-read in pass 2; (c) LDS-accumulator
// aggregation is latency-serial (1404us); (d) wave-per-node CSR gather agg
// is fast (<=129us, r3/r4). One-pass fine bucket partition -> per-bucket
// LDS counting sort -> CSR gather aggs; log_softmax fused into agg2.
// r7/r8: wide masked row-gathers; agg pinned at 3.8 TB/s L2-miss rate =>
// byte-ceilinged. r9: m1/m2 stored bf16 -> agg bytes halved; total 338->236.
// r10: k_gemm1 (69us) was LDS-BW-bound: per k4 the wave moved ~5KB of LDS
// (xs b128 distinct per lane + ws scalar) for 16 FMA = 5x over FMA floor
// (10.4us). Remap lanes: cg=tid&15 owns 4 channels (ws float4, 4-way
// broadcast), r=tid>>4 owns 1 row (xs float4, 16-way broadcast, row pad
// 132 to spread banks). ~1.1KB LDS per wave-k4, FMA-dominant.

#define NN 100000
#define NE 3200000
#define NBUK 391            // ceil(NN/256); bucket b covers cols [b*256 ...)
#define BCAP 8704           // mean 8184, sd ~90; +5.7 sigma slack
#define EPB 16384           // edges per k_bucket block -> 196 blocks

// ---------------- zero (tail) ----------------

__global__ void k_zero(int* __restrict__ p, int n) {
  int i = blockIdx.x * blockDim.x + threadIdx.x;
  if (i < n) p[i] = 0;
}

// ---------------- bf16 helpers ----------------

__device__ __forceinline__ unsigned bf16rne(float x) {
  unsigned u = __float_as_uint(x);
  return (u + 0x7fffu + ((u >> 16) & 1u)) >> 16;
}
__device__ __forceinline__ unsigned pack2(float lo, float hi) {
  return bf16rne(lo) | (bf16rne(hi) << 16);
}

// ---------------- one-pass 391-way bucket partition ----------------

__global__ __launch_bounds__(256) void k_bucket(const int* __restrict__ ei,
                                                int* __restrict__ tail,
                                                unsigned* __restrict__ bucket) {
  __shared__ int hist[NBUK], wbase[NBUK], loc[NBUK];
  const int tid = threadIdx.x;
  const int beg = blockIdx.x * EPB;
  const int end = min(beg + EPB, NE);
  const int* col = ei + NE;
  for (int b = tid; b < NBUK; b += 256) { hist[b] = 0; loc[b] = 0; }
  __syncthreads();
  for (int e = beg + tid * 4; e < end; e += 1024) {
    int4 c4 = *(const int4*)(col + e);
    atomicAdd(&hist[c4.x >> 8], 1);
    atomicAdd(&hist[c4.y >> 8], 1);
    atomicAdd(&hist[c4.z >> 8], 1);
    atomicAdd(&hist[c4.w >> 8], 1);
  }
  __syncthreads();
  for (int b = tid; b < NBUK; b += 256)
    wbase[b] = atomicAdd(&tail[b], hist[b]);   // contiguous block-private run
  __syncthreads();
  for (int e = beg + tid * 4; e < end; e += 1024) {
    int4 c4 = *(const int4*)(col + e);         // L2-hot re-read
    int4 r4 = *(const int4*)(ei + e);
    {
      int b = c4.x >> 8;
      unsigned pos = (unsigned)(wbase[b] + atomicAdd(&loc[b], 1));
      if (pos < BCAP) bucket[(size_t)b * BCAP + pos] = ((unsigned)r4.x << 8) | (unsigned)(c4.x & 255);
    }
    {
      int b = c4.y >> 8;
      unsigned pos = (unsigned)(wbase[b] + atomicAdd(&loc[b], 1));
      if (pos < BCAP) bucket[(size_t)b * BCAP + pos] = ((unsigned)r4.y << 8) | (unsigned)(c4.y & 255);
    }
    {
      int b = c4.z >> 8;
      unsigned pos = (unsigned)(wbase[b] + atomicAdd(&loc[b], 1));
      if (pos < BCAP) bucket[(size_t)b * BCAP + pos] = ((unsigned)r4.z << 8) | (unsigned)(c4.z & 255);
    }
    {
      int b = c4.w >> 8;
      unsigned pos = (unsigned)(wbase[b] + atomicAdd(&loc[b], 1));
      if (pos < BCAP) bucket[(size_t)b * BCAP + pos] = ((unsigned)r4.w << 8) | (unsigned)(c4.w & 255);
    }
  }
}

// ---------------- bucket-start prefix sum (391 elems, 1 block) ----------------

__global__ void k_bstart(const int* __restrict__ tail, int* __restrict__ bstart) {
  const int tid = threadIdx.x, lane = tid & 63, wid = tid >> 6;   // 512 thr
  int v = (tid < NBUK) ? min(tail[tid], BCAP) : 0;
  int s = v;
  #pragma unroll
  for (int d = 1; d < 64; d <<= 1) { int t = __shfl_up(s, d, 64); if (lane >= d) s += t; }
  __shared__ int wsum[8];
  if (lane == 63) wsum[wid] = s;
  __syncthreads();
  int wpre = 0;
  for (int w = 0; w < wid; ++w) wpre += wsum[w];
  int excl = wpre + s - v;
  if (tid <= NBUK) bstart[tid] = excl;     // bstart[NBUK] = total
}

// ---------------- per-bucket LDS counting sort -> CSR + offsets + dinv ----------------

__global__ __launch_bounds__(256) void k_sort(const unsigned* __restrict__ bucket,
                                              const int* __restrict__ tail,
                                              const int* __restrict__ bstart,
                                              int* __restrict__ csr_src,
                                              int* __restrict__ offsets,
                                              float* __restrict__ dinv) {
  __shared__ int h[256], base_[256], loc[256];
  __shared__ int sorted[BCAP];              // 34.8 KB
  __shared__ int wsum[4];
  const int b = blockIdx.x;
  const int lo = b << 8;
  const int nc = min(256, NN - lo);
  const int n = min(tail[b], BCAP);
  const int seg0 = bstart[b];
  const unsigned* __restrict__ bk = bucket + (size_t)b * BCAP;
  const int tid = threadIdx.x, lane = tid & 63, wid = tid >> 6;
  h[tid] = 0; loc[tid] = 0;
  __syncthreads();
  int i = tid * 4;
  for (; i + 3 < n; i += 1024) {
    uint4 v = *(const uint4*)(bk + i);
    atomicAdd(&h[v.x & 255u], 1);
    atomicAdd(&h[v.y & 255u], 1);
    atomicAdd(&h[v.z & 255u], 1);
    atomicAdd(&h[v.w & 255u], 1);
  }
  for (; i < n; ++i) atomicAdd(&h[bk[i] & 255u], 1);
  __syncthreads();
  {  // exclusive scan of h[0..255]
    int v = h[tid];
    int s = v;
    #pragma unroll
    for (int d = 1; d < 64; d <<= 1) { int t = __shfl_up(s, d, 64); if (lane >= d) s += t; }
    if (lane == 63) wsum[wid] = s;
    __syncthreads();
    int wpre = 0;
    #pragma unroll
    for (int w = 0; w < 4; ++w) if (w < wid) wpre += wsum[w];
    int excl = wpre + s - v;
    base_[tid] = excl;
    if (tid < nc) {
      dinv[lo + tid] = rsqrtf((float)(v + 1));       // +1 = self-loop
      offsets[lo + tid] = seg0 + excl;
    }
  }
  if (b == 0 && tid == 0) offsets[NN] = bstart[NBUK];
  __syncthreads();
  i = tid * 4;
  for (; i + 3 < n; i += 1024) {
    uint4 v = *(const uint4*)(bk + i);
    { int c = v.x & 255u; sorted[base_[c] + atomicAdd(&loc[c], 1)] = (int)(v.x >> 8); }
    { int c = v.y & 255u; sorted[base_[c] + atomicAdd(&loc[c], 1)] = (int)(v.y >> 8); }
    { int c = v.z & 255u; sorted[base_[c] + atomicAdd(&loc[c], 1)] = (int)(v.z >> 8); }
    { int c = v.w & 255u; sorted[base_[c] + atomicAdd(&loc[c], 1)] = (int)(v.w >> 8); }
  }
  for (; i < n; ++i) {
    unsigned ent = bk[i];
    int c = ent & 255u;
    sorted[base_[c] + atomicAdd(&loc[c], 1)] = (int)(ent >> 8);
  }
  __syncthreads();
  for (int t = tid; t < n; t += 256) csr_src[seg0 + t] = sorted[t];   // coalesced
}

// ---------------- layer 1 GEMM: m1b = bf16(dinv * (x @ W1)), 128 -> 64 --------
// Lane map: cg = tid&15 -> channels 4cg..4cg+3 (ws float4 read, 4-way
// same-address broadcast across row groups); r = tid>>4 -> row (xs float4
// read, 16-way broadcast). xs rows padded to 132 floats so the 4 distinct
// row addresses per wave land on different bank quads. Per k4: 5 b128
// issues + 16 FMA => FMA-dominant.

__global__ __launch_bounds__(256) void k_gemm1(const float* __restrict__ x,
                                               const float* __restrict__ W1,
                                               const float* __restrict__ dinv,
                                               unsigned* __restrict__ m1b) {
  __shared__ float ws[128 * 64];     // 32 KB, [k][c]
  __shared__ float xs[16 * 132];     // 8.25 KB, row-padded
  const int tid = threadIdx.x;
  for (int k = tid; k < 128 * 64; k += 256) ws[k] = W1[k];
  const int row0 = blockIdx.x * 16;                    // 6250 blocks
  for (int k = tid; k < 16 * 128; k += 256)
    xs[(k >> 7) * 132 + (k & 127)] = x[row0 * 128 + k];
  __syncthreads();
  const int cg = tid & 15;
  const int r = tid >> 4;
  const float4* __restrict__ xr4 = (const float4*)(xs + r * 132);
  const float4* __restrict__ ws4 = (const float4*)ws;   // [k][16] float4
  float4 acc = make_float4(0.f, 0.f, 0.f, 0.f);
  #pragma unroll 8
  for (int k4 = 0; k4 < 32; ++k4) {
    float4 xv = xr4[k4];
    float4 w0 = ws4[(k4 * 4 + 0) * 16 + cg];
    float4 w1 = ws4[(k4 * 4 + 1) * 16 + cg];
    float4 w2 = ws4[(k4 * 4 + 2) * 16 + cg];
    float4 w3 = ws4[(k4 * 4 + 3) * 16 + cg];
    acc.x = fmaf(xv.x, w0.x, fmaf(xv.y, w1.x, fmaf(xv.z, w2.x, fmaf(xv.w, w3.x, acc.x))));
    acc.y = fmaf(xv.x, w0.y, fmaf(xv.y, w1.y, fmaf(xv.z, w2.y, fmaf(xv.w, w3.y, acc.y))));
    acc.z = fmaf(xv.x, w0.z, fmaf(xv.y, w1.z, fmaf(xv.z, w2.z, fmaf(xv.w, w3.z, acc.z))));
    acc.w = fmaf(xv.x, w0.w, fmaf(xv.y, w1.w, fmaf(xv.z, w2.w, fmaf(xv.w, w3.w, acc.w))));
  }
  const float d = dinv[row0 + r];
  uint2 o;
  o.x = pack2(acc.x * d, acc.y * d);   // channels 4cg, 4cg+1 -> u32 slot 2cg
  o.y = pack2(acc.z * d, acc.w * d);   // channels 4cg+2, 4cg+3 -> slot 2cg+1
  ((uint2*)m1b)[(row0 + r) * 16 + cg] = o;
}

// ---------------- unpack-accumulate: uint4 = 8 bf16 channels ----------------

#define ACC8(v, f)                                                   \
  acc[0] = fmaf(__uint_as_float((v).x << 16), (f), acc[0]);          \
  acc[1] = fmaf(__uint_as_float((v).x & 0xffff0000u), (f), acc[1]);  \
  acc[2] = fmaf(__uint_as_float((v).y << 16), (f), acc[2]);          \
  acc[3] = fmaf(__uint_as_float((v).y & 0xffff0000u), (f), acc[3]);  \
  acc[4] = fmaf(__uint_as_float((v).z << 16), (f), acc[4]);          \
  acc[5] = fmaf(__uint_as_float((v).z & 0xffff0000u), (f), acc[5]);  \
  acc[6] = fmaf(__uint_as_float((v).w << 16), (f), acc[6]);          \
  acc[7] = fmaf(__uint_as_float((v).w & 0xffff0000u), (f), acc[7]);

// ---------------- layer 1 aggregation (bf16 rows, 8 rows/instr) -------------
// Lane layout: e = lane>>3 (edge slot 0..7), q = lane&7 (16B chunk = 8 ch).
// Chunk = 32 edges via 4 dwordx4 gathers (8 rows each). Invalid slots clamp
// index to beg and contribute via fma x0.0. fp32 accumulate.

__global__ __launch_bounds__(256) void k_agg1(const unsigned* __restrict__ m1b,
                                              const int* __restrict__ offsets,
                                              const int* __restrict__ csr_src,
                                              const float* __restrict__ dinv,
                                              const float* __restrict__ b1,
                                              float* __restrict__ a1) {
  const int node = blockIdx.x * 4 + (threadIdx.x >> 6);
  const int lane = threadIdx.x & 63;
  const int e = lane >> 3;
  const int q = lane & 7;
  const uint4* __restrict__ m1v = (const uint4*)m1b;
  const int beg = offsets[node], end = offsets[node + 1];
  float acc[8];
  #pragma unroll
  for (int j = 0; j < 8; ++j) acc[j] = 0.f;
  for (int p = beg; p < end; p += 32) {
    const int i0 = p + e, i1 = p + 8 + e, i2 = p + 16 + e, i3 = p + 24 + e;
    const int s0 = csr_src[i0 < end ? i0 : beg];
    const int s1 = csr_src[i1 < end ? i1 : beg];
    const int s2 = csr_src[i2 < end ? i2 : beg];
    const int s3 = csr_src[i3 < end ? i3 : beg];
    const float f0 = (i0 < end) ? 1.f : 0.f;
    const float f1 = (i1 < end) ? 1.f : 0.f;
    const float f2 = (i2 < end) ? 1.f : 0.f;
    const float f3 = (i3 < end) ? 1.f : 0.f;
    uint4 v0 = m1v[s0 * 8 + q];
    uint4 v1 = m1v[s1 * 8 + q];
    uint4 v2 = m1v[s2 * 8 + q];
    uint4 v3 = m1v[s3 * 8 + q];
    ACC8(v0, f0);
    ACC8(v1, f1);
    ACC8(v2, f2);
    ACC8(v3, f3);
  }
  // reduce the 8 edge slots; channel chunk q stays put
  #pragma unroll
  for (int j = 0; j < 8; ++j) {
    acc[j] += __shfl_xor(acc[j], 8, 64);
    acc[j] += __shfl_xor(acc[j], 16, 64);
    acc[j] += __shfl_xor(acc[j], 32, 64);
  }
  if (e == 0) {                       // lanes 0..7 hold chunk q = lane
    uint4 sv = m1v[node * 8 + q];     // self-loop row
    const float d = dinv[node];
    float4 bb0 = ((const float4*)b1)[q * 2];
    float4 bb1 = ((const float4*)b1)[q * 2 + 1];
    float4 o0, o1;
    o0.x = (acc[0] + __uint_as_float(sv.x << 16)) * d + bb0.x;
    o0.y = (acc[1] + __uint_as_float(sv.x & 0xffff0000u)) * d + bb0.y;
    o0.z = (acc[2] + __uint_as_float(sv.y << 16)) * d + bb0.z;
    o0.w = (acc[3] + __uint_as_float(sv.y & 0xffff0000u)) * d + bb0.w;
    o1.x = (acc[4] + __uint_as_float(sv.z << 16)) * d + bb1.x;
    o1.y = (acc[5] + __uint_as_float(sv.z & 0xffff0000u)) * d + bb1.y;
    o1.z = (acc[6] + __uint_as_float(sv.w << 16)) * d + bb1.z;
    o1.w = (acc[7] + __uint_as_float(sv.w & 0xffff0000u)) * d + bb1.w;
    ((float4*)a1)[node * 16 + q * 2] = o0;
    ((float4*)a1)[node * 16 + q * 2 + 1] = o1;
  }
}

// ---------------- layer 2 GEMM: m2b = bf16(dinv * (a1 @ W2)), 64 -> 40 ------

__global__ __launch_bounds__(256) void k_gemm2(const float* __restrict__ a1,
                                               const float* __restrict__ W2,
                                               const float* __restrict__ dinv,
                                               unsigned* __restrict__ m2b) {
  __shared__ float ws[64 * 40];    // 10 KB
  const int tid = threadIdx.x;
  for (int k = tid; k < 64 * 40; k += 256) ws[k] = W2[k];
  __syncthreads();
  const int idx = blockIdx.x * 256 + tid;                // thread = (node, ch-pair)
  if (idx >= NN * 20) return;
  const int node = idx / 20;
  const int c0 = (idx - node * 20) * 2;
  const float4* __restrict__ a4 = (const float4*)(a1 + node * 64);
  float acc0 = 0.f, acc1 = 0.f;
  #pragma unroll
  for (int k4 = 0; k4 < 16; ++k4) {
    float4 a = a4[k4];
    acc0 = fmaf(a.x, ws[(k4 * 4 + 0) * 40 + c0], acc0);
    acc1 = fmaf(a.x, ws[(k4 * 4 + 0) * 40 + c0 + 1], acc1);
    acc0 = fmaf(a.y, ws[(k4 * 4 + 1) * 40 + c0], acc0);
    acc1 = fmaf(a.y, ws[(k4 * 4 + 1) * 40 + c0 + 1], acc1);
    acc0 = fmaf(a.z, ws[(k4 * 4 + 2) * 40 + c0], acc0);
    acc1 = fmaf(a.z, ws[(k4 * 4 + 2) * 40 + c0 + 1], acc1);
    acc0 = fmaf(a.w, ws[(k4 * 4 + 3) * 40 + c0], acc0);
    acc1 = fmaf(a.w, ws[(k4 * 4 + 3) * 40 + c0 + 1], acc1);
  }
  const float d = dinv[node];
  m2b[idx] = pack2(acc0 * d, acc1 * d);
}

// ---------------- layer 2 aggregation + bias + log_softmax ------------------
// Lane layout: e = lane/5 (edge slot 0..11), q = lane%5 (16B chunk = 8 ch);
// lanes 60..63 masked (f=0). Chunk = 48 edges via 4 dwordx4 gathers (12
// rows each). Reduce 12 slots via shfl (+30, +15, +5/+10); log_softmax
// over 5 lanes x 8 comps via width-8 xor (lanes 5..7 seeded -inf/0).

__device__ __forceinline__ float shfl1(float v, int src) {
  return __shfl(v, src & 63, 64);
}

__global__ __launch_bounds__(256) void k_agg2(const unsigned* __restrict__ m2b,
                                              const int* __restrict__ offsets,
                                              const int* __restrict__ csr_src,
                                              const float* __restrict__ dinv,
                                              const float* __restrict__ b2,
                                              float* __restrict__ out) {
  const int node = blockIdx.x * 4 + (threadIdx.x >> 6);
  const int lane = threadIdx.x & 63;
  const bool act = lane < 60;
  const int e = act ? (lane / 5) : 0;
  const int q = act ? (lane - e * 5) : 0;
  const uint4* __restrict__ m2v = (const uint4*)m2b;
  const int beg = offsets[node], end = offsets[node + 1];
  float acc[8];
  #pragma unroll
  for (int j = 0; j < 8; ++j) acc[j] = 0.f;
  for (int p = beg; p < end; p += 48) {
    const int i0 = p + e, i1 = p + 12 + e, i2 = p + 24 + e, i3 = p + 36 + e;
    const int s0 = csr_src[i0 < end ? i0 : beg];
    const int s1 = csr_src[i1 < end ? i1 : beg];
    const int s2 = csr_src[i2 < end ? i2 : beg];
    const int s3 = csr_src[i3 < end ? i3 : beg];
    const float f0 = (act && i0 < end) ? 1.f : 0.f;
    const float f1 = (act && i1 < end) ? 1.f : 0.f;
    const float f2 = (act && i2 < end) ? 1.f : 0.f;
    const float f3 = (act && i3 < end) ? 1.f : 0.f;
    uint4 v0 = m2v[s0 * 5 + q];
    uint4 v1 = m2v[s1 * 5 + q];
    uint4 v2 = m2v[s2 * 5 + q];
    uint4 v3 = m2v[s3 * 5 + q];
    ACC8(v0, f0);
    ACC8(v1, f1);
    ACC8(v2, f2);
    ACC8(v3, f3);
  }
  // reduce 12 slots: lanes 0..29 += lanes+30; lanes 0..14 += lanes+15;
  // lanes 0..4 += lanes+5 and lanes+10
  #pragma unroll
  for (int j = 0; j < 8; ++j) acc[j] += shfl1(acc[j], lane + 30);
  #pragma unroll
  for (int j = 0; j < 8; ++j) acc[j] += shfl1(acc[j], lane + 15);
  #pragma unroll
  for (int j = 0; j < 8; ++j) {
    float t1 = shfl1(acc[j], lane + 5);
    float t2 = shfl1(acc[j], lane + 10);
    acc[j] += t1 + t2;
  }
  const bool lead = (lane < 5);
  float r[8];
  #pragma unroll
  for (int j = 0; j < 8; ++j) r[j] = 0.f;
  if (lead) {
    uint4 sv = m2v[node * 5 + lane];   // self-loop row (q == lane here)
    const float d = dinv[node];
    float4 bb0 = ((const float4*)b2)[lane * 2];
    float4 bb1 = ((const float4*)b2)[lane * 2 + 1];
    r[0] = (acc[0] + __uint_as_float(sv.x << 16)) * d + bb0.x;
    r[1] = (acc[1] + __uint_as_float(sv.x & 0xffff0000u)) * d + bb0.y;
    r[2] = (acc[2] + __uint_as_float(sv.y << 16)) * d + bb0.z;
    r[3] = (acc[3] + __uint_as_float(sv.y & 0xffff0000u)) * d + bb0.w;
    r[4] = (acc[4] + __uint_as_float(sv.z << 16)) * d + bb1.x;
    r[5] = (acc[5] + __uint_as_float(sv.z & 0xffff0000u)) * d + bb1.y;
    r[6] = (acc[6] + __uint_as_float(sv.w << 16)) * d + bb1.z;
    r[7] = (acc[7] + __uint_as_float(sv.w & 0xffff0000u)) * d + bb1.w;
  }
  // log_softmax over 40 = 5 lanes x 8 comps (width-8 xor; lanes 5..7 seeded)
  float mx = -INFINITY;
  if (lead) {
    mx = fmaxf(fmaxf(fmaxf(r[0], r[1]), fmaxf(r[2], r[3])),
               fmaxf(fmaxf(r[4], r[5]), fmaxf(r[6], r[7])));
  }
  #pragma unroll
  for (int d = 4; d > 0; d >>= 1) mx = fmaxf(mx, __shfl_xor(mx, d, 8));
  float se = 0.f;
  if (lead) {
    se = __expf(r[0] - mx) + __expf(r[1] - mx) + __expf(r[2] - mx) +
         __expf(r[3] - mx) + __expf(r[4] - mx) + __expf(r[5] - mx) +
         __expf(r[6] - mx) + __expf(r[7] - mx);
  }
  #pragma unroll
  for (int d = 4; d > 0; d >>= 1) se += __shfl_xor(se, d, 8);
  if (lead) {
    const float lse = mx + logf(se);
    float4 o0, o1;
    o0.x = r[0] - lse; o0.y = r[1] - lse; o0.z = r[2] - lse; o0.w = r[3] - lse;
    o1.x = r[4] - lse; o1.y = r[5] - lse; o1.z = r[6] - lse; o1.w = r[7] - lse;
    ((float4*)out)[node * 10 + lane * 2] = o0;
    ((float4*)out)[node * 10 + lane * 2 + 1] = o1;
  }
}

// ---------------- launch ----------------

extern "C" void kernel_launch(void* const* d_in, const int* in_sizes, int n_in,
                              void* d_out, int out_size, void* d_ws, size_t ws_size,
                              hipStream_t stream) {
  const float* x   = (const float*)d_in[0];
  const int*   ei  = (const int*)d_in[1];   // [2][NE], int32
  const float* W1  = (const float*)d_in[3];
  const float* b1  = (const float*)d_in[4];
  const float* W2  = (const float*)d_in[5];
  const float* b2  = (const float*)d_in[6];
  float*       out = (float*)d_out;

  char* ws = (char*)d_ws;
  int*      tail    = (int*)(ws + 0);                            // NBUK ints
  int*      bstart  = (int*)(ws + (size_t)4 * 1024);             // NBUK+1 ints
  int*      offsets = (int*)(ws + (size_t)8 * 1024);             // (NN+1)*4 = 400KB
  float*    dinv    = (float*)(ws + (size_t)512 * 1024);         // NN*4 = 400KB
  int*      csr_src = (int*)(ws + (size_t)1024 * 1024);          // NE*4 = 12.8MB
  unsigned* bucket  = (unsigned*)(ws + (size_t)14 * 1024 * 1024);// 13.6MB, dead after k_sort
  unsigned* m1b     = (unsigned*)(ws + (size_t)14 * 1024 * 1024);// 12.8MB bf16 (overlays bucket)
  float*    a1      = (float*)(ws + (size_t)40 * 1024 * 1024);   // 25.6MB fp32
  unsigned* m2b     = m1b;  // m1b dead after agg1 (NN*20*4 = 8MB)

  k_zero<<<2, 256, 0, stream>>>(tail, NBUK);
  k_bucket<<<(NE + EPB - 1) / EPB, 256, 0, stream>>>(ei, tail, bucket);
  k_bstart<<<1, 512, 0, stream>>>(tail, bstart);
  k_sort<<<NBUK, 256, 0, stream>>>(bucket, tail, bstart, csr_src, offsets, dinv);
  k_gemm1<<<NN / 16, 256, 0, stream>>>(x, W1, dinv, m1b);
  k_agg1<<<NN / 4, 256, 0, stream>>>(m1b, offsets, csr_src, dinv, b1, a1);
  k_gemm2<<<(NN * 20 + 255) / 256, 256, 0, stream>>>(a1, W2, dinv, m2b);
  k_agg2<<<NN / 4, 256, 0, stream>>>(m2b, offsets, csr_src, dinv, b2, out);
}

// Round 5
// 233.113 us; speedup vs baseline: 1.0185x; 1.0185x over previous
//
#include <hip/hip_runtime.h>
#include <math.h>

// GCN 2-layer forward on MI355X.
// Lessons r2-r6: (a) random 4B global stores => ~130MB writebacks however
// sharded; (b) coarse buckets => 32x re-read in pass 2; (c) LDS-accumulator
// aggregation is latency-serial (1404us); (d) wave-per-node CSR gather agg
// is fast (<=129us, r3/r4). One-pass fine bucket partition -> per-bucket
// LDS counting sort -> CSR gather aggs; log_softmax fused into agg2.
// r7/r8: wide masked row-gathers; agg pinned at 3.8 TB/s L2-miss rate =>
// byte-ceilinged. r9: m1/m2 stored bf16 -> agg bytes halved; total 338->236.
// r10 FAILED: broadcast remap of gemm1 didn't move LDS bytes/FMA (5KB per
// 16 FMA per wave both ways); 4GB LDS traffic / 69TB/s = 58us ~= measured
// 70us => gemm1 is LDS-return-bandwidth bound.
// r11: 8x8 register tiling: per k each thread reads 2 float4 x-rows
// (transposed slice xt[k][row], pad 132) + 2 float4 w-channels = 64B for
// 64 FMA (5x fewer LDS bytes/FMA). 128-thr blocks, 782 blocks, 41KB LDS.

#define NN 100000
#define NE 3200000
#define NBUK 391            // ceil(NN/256); bucket b covers cols [b*256 ...)
#define BCAP 8704           // mean 8184, sd ~90; +5.7 sigma slack
#define EPB 16384           // edges per k_bucket block -> 196 blocks

// ---------------- zero (tail) ----------------

__global__ void k_zero(int* __restrict__ p, int n) {
  int i = blockIdx.x * blockDim.x + threadIdx.x;
  if (i < n) p[i] = 0;
}

// ---------------- bf16 helpers ----------------

__device__ __forceinline__ unsigned bf16rne(float x) {
  unsigned u = __float_as_uint(x);
  return (u + 0x7fffu + ((u >> 16) & 1u)) >> 16;
}
__device__ __forceinline__ unsigned pack2(float lo, float hi) {
  return bf16rne(lo) | (bf16rne(hi) << 16);
}

// ---------------- one-pass 391-way bucket partition ----------------

__global__ __launch_bounds__(256) void k_bucket(const int* __restrict__ ei,
                                                int* __restrict__ tail,
                                                unsigned* __restrict__ bucket) {
  __shared__ int hist[NBUK], wbase[NBUK], loc[NBUK];
  const int tid = threadIdx.x;
  const int beg = blockIdx.x * EPB;
  const int end = min(beg + EPB, NE);
  const int* col = ei + NE;
  for (int b = tid; b < NBUK; b += 256) { hist[b] = 0; loc[b] = 0; }
  __syncthreads();
  for (int e = beg + tid * 4; e < end; e += 1024) {
    int4 c4 = *(const int4*)(col + e);
    atomicAdd(&hist[c4.x >> 8], 1);
    atomicAdd(&hist[c4.y >> 8], 1);
    atomicAdd(&hist[c4.z >> 8], 1);
    atomicAdd(&hist[c4.w >> 8], 1);
  }
  __syncthreads();
  for (int b = tid; b < NBUK; b += 256)
    wbase[b] = atomicAdd(&tail[b], hist[b]);   // contiguous block-private run
  __syncthreads();
  for (int e = beg + tid * 4; e < end; e += 1024) {
    int4 c4 = *(const int4*)(col + e);         // L2-hot re-read
    int4 r4 = *(const int4*)(ei + e);
    {
      int b = c4.x >> 8;
      unsigned pos = (unsigned)(wbase[b] + atomicAdd(&loc[b], 1));
      if (pos < BCAP) bucket[(size_t)b * BCAP + pos] = ((unsigned)r4.x << 8) | (unsigned)(c4.x & 255);
    }
    {
      int b = c4.y >> 8;
      unsigned pos = (unsigned)(wbase[b] + atomicAdd(&loc[b], 1));
      if (pos < BCAP) bucket[(size_t)b * BCAP + pos] = ((unsigned)r4.y << 8) | (unsigned)(c4.y & 255);
    }
    {
      int b = c4.z >> 8;
      unsigned pos = (unsigned)(wbase[b] + atomicAdd(&loc[b], 1));
      if (pos < BCAP) bucket[(size_t)b * BCAP + pos] = ((unsigned)r4.z << 8) | (unsigned)(c4.z & 255);
    }
    {
      int b = c4.w >> 8;
      unsigned pos = (unsigned)(wbase[b] + atomicAdd(&loc[b], 1));
      if (pos < BCAP) bucket[(size_t)b * BCAP + pos] = ((unsigned)r4.w << 8) | (unsigned)(c4.w & 255);
    }
  }
}

// ---------------- bucket-start prefix sum (391 elems, 1 block) ----------------

__global__ void k_bstart(const int* __restrict__ tail, int* __restrict__ bstart) {
  const int tid = threadIdx.x, lane = tid & 63, wid = tid >> 6;   // 512 thr
  int v = (tid < NBUK) ? min(tail[tid], BCAP) : 0;
  int s = v;
  #pragma unroll
  for (int d = 1; d < 64; d <<= 1) { int t = __shfl_up(s, d, 64); if (lane >= d) s += t; }
  __shared__ int wsum[8];
  if (lane == 63) wsum[wid] = s;
  __syncthreads();
  int wpre = 0;
  for (int w = 0; w < wid; ++w) wpre += wsum[w];
  int excl = wpre + s - v;
  if (tid <= NBUK) bstart[tid] = excl;     // bstart[NBUK] = total
}

// ---------------- per-bucket LDS counting sort -> CSR + offsets + dinv ----------------

__global__ __launch_bounds__(256) void k_sort(const unsigned* __restrict__ bucket,
                                              const int* __restrict__ tail,
                                              const int* __restrict__ bstart,
                                              int* __restrict__ csr_src,
                                              int* __restrict__ offsets,
                                              float* __restrict__ dinv) {
  __shared__ int h[256], base_[256], loc[256];
  __shared__ int sorted[BCAP];              // 34.8 KB
  __shared__ int wsum[4];
  const int b = blockIdx.x;
  const int lo = b << 8;
  const int nc = min(256, NN - lo);
  const int n = min(tail[b], BCAP);
  const int seg0 = bstart[b];
  const unsigned* __restrict__ bk = bucket + (size_t)b * BCAP;
  const int tid = threadIdx.x, lane = tid & 63, wid = tid >> 6;
  h[tid] = 0; loc[tid] = 0;
  __syncthreads();
  int i = tid * 4;
  for (; i + 3 < n; i += 1024) {
    uint4 v = *(const uint4*)(bk + i);
    atomicAdd(&h[v.x & 255u], 1);
    atomicAdd(&h[v.y & 255u], 1);
    atomicAdd(&h[v.z & 255u], 1);
    atomicAdd(&h[v.w & 255u], 1);
  }
  for (; i < n; ++i) atomicAdd(&h[bk[i] & 255u], 1);
  __syncthreads();
  {  // exclusive scan of h[0..255]
    int v = h[tid];
    int s = v;
    #pragma unroll
    for (int d = 1; d < 64; d <<= 1) { int t = __shfl_up(s, d, 64); if (lane >= d) s += t; }
    if (lane == 63) wsum[wid] = s;
    __syncthreads();
    int wpre = 0;
    #pragma unroll
    for (int w = 0; w < 4; ++w) if (w < wid) wpre += wsum[w];
    int excl = wpre + s - v;
    base_[tid] = excl;
    if (tid < nc) {
      dinv[lo + tid] = rsqrtf((float)(v + 1));       // +1 = self-loop
      offsets[lo + tid] = seg0 + excl;
    }
  }
  if (b == 0 && tid == 0) offsets[NN] = bstart[NBUK];
  __syncthreads();
  i = tid * 4;
  for (; i + 3 < n; i += 1024) {
    uint4 v = *(const uint4*)(bk + i);
    { int c = v.x & 255u; sorted[base_[c] + atomicAdd(&loc[c], 1)] = (int)(v.x >> 8); }
    { int c = v.y & 255u; sorted[base_[c] + atomicAdd(&loc[c], 1)] = (int)(v.y >> 8); }
    { int c = v.z & 255u; sorted[base_[c] + atomicAdd(&loc[c], 1)] = (int)(v.z >> 8); }
    { int c = v.w & 255u; sorted[base_[c] + atomicAdd(&loc[c], 1)] = (int)(v.w >> 8); }
  }
  for (; i < n; ++i) {
    unsigned ent = bk[i];
    int c = ent & 255u;
    sorted[base_[c] + atomicAdd(&loc[c], 1)] = (int)(ent >> 8);
  }
  __syncthreads();
  for (int t = tid; t < n; t += 256) csr_src[seg0 + t] = sorted[t];   // coalesced
}

// ---------------- layer 1 GEMM: m1b = bf16(dinv * (x @ W1)), 128 -> 64 --------
// 8x8 register tile per thread. cg = tid&7 -> ch 8cg..8cg+7; rg = tid>>3 ->
// rows 8rg..8rg+7. x staged transposed per 16-k slice: xt[k][row], row dim
// padded to 132 (2-way bank aliasing only). Per k: 4 ds_read_b128 -> 64 FMA.

__global__ __launch_bounds__(128) void k_gemm1(const float* __restrict__ x,
                                               const float* __restrict__ W1,
                                               const float* __restrict__ dinv,
                                               unsigned* __restrict__ m1b) {
  __shared__ float ws[128 * 64];      // 32 KB, [k][c]
  __shared__ float xt[16 * 132];      // 8.25 KB, [k within slice][row padded]
  const int tid = threadIdx.x;
  const int row0 = blockIdx.x * 128;  // 782 blocks
  {
    const float4* __restrict__ w4 = (const float4*)W1;
    float4* __restrict__ s4 = (float4*)ws;
    for (int i = tid; i < 128 * 16; i += 128) s4[i] = w4[i];
  }
  const int cg = tid & 7;
  const int rg = tid >> 3;            // 0..15
  const int lr = tid >> 2;            // load: row within 32-row group
  const int lk = tid & 3;             // load: k-quad
  float acc[8][8];
  #pragma unroll
  for (int i = 0; i < 8; ++i)
    #pragma unroll
    for (int j = 0; j < 8; ++j) acc[i][j] = 0.f;
  const float4* __restrict__ xt4 = (const float4*)xt;
  const float4* __restrict__ ws4 = (const float4*)ws;
  for (int ks = 0; ks < 8; ++ks) {
    __syncthreads();
    // stage 128 rows x 16 k, transposed
    #pragma unroll
    for (int it = 0; it < 4; ++it) {
      const int row = it * 32 + lr;
      int grow = row0 + row; if (grow > NN - 1) grow = NN - 1;
      float4 v = *(const float4*)(x + (size_t)grow * 128 + ks * 16 + lk * 4);
      xt[(lk * 4 + 0) * 132 + row] = v.x;
      xt[(lk * 4 + 1) * 132 + row] = v.y;
      xt[(lk * 4 + 2) * 132 + row] = v.z;
      xt[(lk * 4 + 3) * 132 + row] = v.w;
    }
    __syncthreads();
    #pragma unroll 2
    for (int kk = 0; kk < 16; ++kk) {
      const int k = ks * 16 + kk;
      float4 xa = xt4[kk * 33 + rg * 2];
      float4 xb = xt4[kk * 33 + rg * 2 + 1];
      float4 wa = ws4[k * 16 + cg * 2];
      float4 wb = ws4[k * 16 + cg * 2 + 1];
      float xr[8] = {xa.x, xa.y, xa.z, xa.w, xb.x, xb.y, xb.z, xb.w};
      float wc[8] = {wa.x, wa.y, wa.z, wa.w, wb.x, wb.y, wb.z, wb.w};
      #pragma unroll
      for (int i = 0; i < 8; ++i)
        #pragma unroll
        for (int j = 0; j < 8; ++j)
          acc[i][j] = fmaf(xr[i], wc[j], acc[i][j]);
    }
  }
  #pragma unroll
  for (int i = 0; i < 8; ++i) {
    const int row = row0 + rg * 8 + i;
    if (row < NN) {
      const float d = dinv[row];
      uint4 o;
      o.x = pack2(acc[i][0] * d, acc[i][1] * d);
      o.y = pack2(acc[i][2] * d, acc[i][3] * d);
      o.z = pack2(acc[i][4] * d, acc[i][5] * d);
      o.w = pack2(acc[i][6] * d, acc[i][7] * d);
      ((uint4*)m1b)[row * 8 + cg] = o;   // ch 8cg..8cg+7 = u32 slots 4cg..4cg+3
    }
  }
}

// ---------------- unpack-accumulate: uint4 = 8 bf16 channels ----------------

#define ACC8(v, f)                                                   \
  acc[0] = fmaf(__uint_as_float((v).x << 16), (f), acc[0]);          \
  acc[1] = fmaf(__uint_as_float((v).x & 0xffff0000u), (f), acc[1]);  \
  acc[2] = fmaf(__uint_as_float((v).y << 16), (f), acc[2]);          \
  acc[3] = fmaf(__uint_as_float((v).y & 0xffff0000u), (f), acc[3]);  \
  acc[4] = fmaf(__uint_as_float((v).z << 16), (f), acc[4]);          \
  acc[5] = fmaf(__uint_as_float((v).z & 0xffff0000u), (f), acc[5]);  \
  acc[6] = fmaf(__uint_as_float((v).w << 16), (f), acc[6]);          \
  acc[7] = fmaf(__uint_as_float((v).w & 0xffff0000u), (f), acc[7]);

// ---------------- layer 1 aggregation (bf16 rows, 8 rows/instr) -------------
// Lane layout: e = lane>>3 (edge slot 0..7), q = lane&7 (16B chunk = 8 ch).
// Chunk = 32 edges via 4 dwordx4 gathers (8 rows each). Invalid slots clamp
// index to beg and contribute via fma x0.0. fp32 accumulate.

__global__ __launch_bounds__(256) void k_agg1(const unsigned* __restrict__ m1b,
                                              const int* __restrict__ offsets,
                                              const int* __restrict__ csr_src,
                                              const float* __restrict__ dinv,
                                              const float* __restrict__ b1,
                                              float* __restrict__ a1) {
  const int node = blockIdx.x * 4 + (threadIdx.x >> 6);
  const int lane = threadIdx.x & 63;
  const int e = lane >> 3;
  const int q = lane & 7;
  const uint4* __restrict__ m1v = (const uint4*)m1b;
  const int beg = offsets[node], end = offsets[node + 1];
  float acc[8];
  #pragma unroll
  for (int j = 0; j < 8; ++j) acc[j] = 0.f;
  for (int p = beg; p < end; p += 32) {
    const int i0 = p + e, i1 = p + 8 + e, i2 = p + 16 + e, i3 = p + 24 + e;
    const int s0 = csr_src[i0 < end ? i0 : beg];
    const int s1 = csr_src[i1 < end ? i1 : beg];
    const int s2 = csr_src[i2 < end ? i2 : beg];
    const int s3 = csr_src[i3 < end ? i3 : beg];
    const float f0 = (i0 < end) ? 1.f : 0.f;
    const float f1 = (i1 < end) ? 1.f : 0.f;
    const float f2 = (i2 < end) ? 1.f : 0.f;
    const float f3 = (i3 < end) ? 1.f : 0.f;
    uint4 v0 = m1v[s0 * 8 + q];
    uint4 v1 = m1v[s1 * 8 + q];
    uint4 v2 = m1v[s2 * 8 + q];
    uint4 v3 = m1v[s3 * 8 + q];
    ACC8(v0, f0);
    ACC8(v1, f1);
    ACC8(v2, f2);
    ACC8(v3, f3);
  }
  // reduce the 8 edge slots; channel chunk q stays put
  #pragma unroll
  for (int j = 0; j < 8; ++j) {
    acc[j] += __shfl_xor(acc[j], 8, 64);
    acc[j] += __shfl_xor(acc[j], 16, 64);
    acc[j] += __shfl_xor(acc[j], 32, 64);
  }
  if (e == 0) {                       // lanes 0..7 hold chunk q = lane
    uint4 sv = m1v[node * 8 + q];     // self-loop row
    const float d = dinv[node];
    float4 bb0 = ((const float4*)b1)[q * 2];
    float4 bb1 = ((const float4*)b1)[q * 2 + 1];
    float4 o0, o1;
    o0.x = (acc[0] + __uint_as_float(sv.x << 16)) * d + bb0.x;
    o0.y = (acc[1] + __uint_as_float(sv.x & 0xffff0000u)) * d + bb0.y;
    o0.z = (acc[2] + __uint_as_float(sv.y << 16)) * d + bb0.z;
    o0.w = (acc[3] + __uint_as_float(sv.y & 0xffff0000u)) * d + bb0.w;
    o1.x = (acc[4] + __uint_as_float(sv.z << 16)) * d + bb1.x;
    o1.y = (acc[5] + __uint_as_float(sv.z & 0xffff0000u)) * d + bb1.y;
    o1.z = (acc[6] + __uint_as_float(sv.w << 16)) * d + bb1.z;
    o1.w = (acc[7] + __uint_as_float(sv.w & 0xffff0000u)) * d + bb1.w;
    ((float4*)a1)[node * 16 + q * 2] = o0;
    ((float4*)a1)[node * 16 + q * 2 + 1] = o1;
  }
}

// ---------------- layer 2 GEMM: m2b = bf16(dinv * (a1 @ W2)), 64 -> 40 ------

__global__ __launch_bounds__(256) void k_gemm2(const float* __restrict__ a1,
                                               const float* __restrict__ W2,
                                               const float* __restrict__ dinv,
                                               unsigned* __restrict__ m2b) {
  __shared__ float ws[64 * 40];    // 10 KB
  const int tid = threadIdx.x;
  for (int k = tid; k < 64 * 40; k += 256) ws[k] = W2[k];
  __syncthreads();
  const int idx = blockIdx.x * 256 + tid;                // thread = (node, ch-pair)
  if (idx >= NN * 20) return;
  const int node = idx / 20;
  const int c0 = (idx - node * 20) * 2;
  const float4* __restrict__ a4 = (const float4*)(a1 + node * 64);
  float acc0 = 0.f, acc1 = 0.f;
  #pragma unroll
  for (int k4 = 0; k4 < 16; ++k4) {
    float4 a = a4[k4];
    acc0 = fmaf(a.x, ws[(k4 * 4 + 0) * 40 + c0], acc0);
    acc1 = fmaf(a.x, ws[(k4 * 4 + 0) * 40 + c0 + 1], acc1);
    acc0 = fmaf(a.y, ws[(k4 * 4 + 1) * 40 + c0], acc0);
    acc1 = fmaf(a.y, ws[(k4 * 4 + 1) * 40 + c0 + 1], acc1);
    acc0 = fmaf(a.z, ws[(k4 * 4 + 2) * 40 + c0], acc0);
    acc1 = fmaf(a.z, ws[(k4 * 4 + 2) * 40 + c0 + 1], acc1);
    acc0 = fmaf(a.w, ws[(k4 * 4 + 3) * 40 + c0], acc0);
    acc1 = fmaf(a.w, ws[(k4 * 4 + 3) * 40 + c0 + 1], acc1);
  }
  const float d = dinv[node];
  m2b[idx] = pack2(acc0 * d, acc1 * d);
}

// ---------------- layer 2 aggregation + bias + log_softmax ------------------
// Lane layout: e = lane/5 (edge slot 0..11), q = lane%5 (16B chunk = 8 ch);
// lanes 60..63 masked (f=0). Chunk = 48 edges via 4 dwordx4 gathers (12
// rows each). Reduce 12 slots via shfl (+30, +15, +5/+10); log_softmax
// over 5 lanes x 8 comps via width-8 xor (lanes 5..7 seeded -inf/0).

__device__ __forceinline__ float shfl1(float v, int src) {
  return __shfl(v, src & 63, 64);
}

__global__ __launch_bounds__(256) void k_agg2(const unsigned* __restrict__ m2b,
                                              const int* __restrict__ offsets,
                                              const int* __restrict__ csr_src,
                                              const float* __restrict__ dinv,
                                              const float* __restrict__ b2,
                                              float* __restrict__ out) {
  const int node = blockIdx.x * 4 + (threadIdx.x >> 6);
  const int lane = threadIdx.x & 63;
  const bool act = lane < 60;
  const int e = act ? (lane / 5) : 0;
  const int q = act ? (lane - e * 5) : 0;
  const uint4* __restrict__ m2v = (const uint4*)m2b;
  const int beg = offsets[node], end = offsets[node + 1];
  float acc[8];
  #pragma unroll
  for (int j = 0; j < 8; ++j) acc[j] = 0.f;
  for (int p = beg; p < end; p += 48) {
    const int i0 = p + e, i1 = p + 12 + e, i2 = p + 24 + e, i3 = p + 36 + e;
    const int s0 = csr_src[i0 < end ? i0 : beg];
    const int s1 = csr_src[i1 < end ? i1 : beg];
    const int s2 = csr_src[i2 < end ? i2 : beg];
    const int s3 = csr_src[i3 < end ? i3 : beg];
    const float f0 = (act && i0 < end) ? 1.f : 0.f;
    const float f1 = (act && i1 < end) ? 1.f : 0.f;
    const float f2 = (act && i2 < end) ? 1.f : 0.f;
    const float f3 = (act && i3 < end) ? 1.f : 0.f;
    uint4 v0 = m2v[s0 * 5 + q];
    uint4 v1 = m2v[s1 * 5 + q];
    uint4 v2 = m2v[s2 * 5 + q];
    uint4 v3 = m2v[s3 * 5 + q];
    ACC8(v0, f0);
    ACC8(v1, f1);
    ACC8(v2, f2);
    ACC8(v3, f3);
  }
  // reduce 12 slots: lanes 0..29 += lanes+30; lanes 0..14 += lanes+15;
  // lanes 0..4 += lanes+5 and lanes+10
  #pragma unroll
  for (int j = 0; j < 8; ++j) acc[j] += shfl1(acc[j], lane + 30);
  #pragma unroll
  for (int j = 0; j < 8; ++j) acc[j] += shfl1(acc[j], lane + 15);
  #pragma unroll
  for (int j = 0; j < 8; ++j) {
    float t1 = shfl1(acc[j], lane + 5);
    float t2 = shfl1(acc[j], lane + 10);
    acc[j] += t1 + t2;
  }
  const bool lead = (lane < 5);
  float r[8];
  #pragma unroll
  for (int j = 0; j < 8; ++j) r[j] = 0.f;
  if (lead) {
    uint4 sv = m2v[node * 5 + lane];   // self-loop row (q == lane here)
    const float d = dinv[node];
    float4 bb0 = ((const float4*)b2)[lane * 2];
    float4 bb1 = ((const float4*)b2)[lane * 2 + 1];
    r[0] = (acc[0] + __uint_as_float(sv.x << 16)) * d + bb0.x;
    r[1] = (acc[1] + __uint_as_float(sv.x & 0xffff0000u)) * d + bb0.y;
    r[2] = (acc[2] + __uint_as_float(sv.y << 16)) * d + bb0.z;
    r[3] = (acc[3] + __uint_as_float(sv.y & 0xffff0000u)) * d + bb0.w;
    r[4] = (acc[4] + __uint_as_float(sv.z << 16)) * d + bb1.x;
    r[5] = (acc[5] + __uint_as_float(sv.z & 0xffff0000u)) * d + bb1.y;
    r[6] = (acc[6] + __uint_as_float(sv.w << 16)) * d + bb1.z;
    r[7] = (acc[7] + __uint_as_float(sv.w & 0xffff0000u)) * d + bb1.w;
  }
  // log_softmax over 40 = 5 lanes x 8 comps (width-8 xor; lanes 5..7 seeded)
  float mx = -INFINITY;
  if (lead) {
    mx = fmaxf(fmaxf(fmaxf(r[0], r[1]), fmaxf(r[2], r[3])),
               fmaxf(fmaxf(r[4], r[5]), fmaxf(r[6], r[7])));
  }
  #pragma unroll
  for (int d = 4; d > 0; d >>= 1) mx = fmaxf(mx, __shfl_xor(mx, d, 8));
  float se = 0.f;
  if (lead) {
    se = __expf(r[0] - mx) + __expf(r[1] - mx) + __expf(r[2] - mx) +
         __expf(r[3] - mx) + __expf(r[4] - mx) + __expf(r[5] - mx) +
         __expf(r[6] - mx) + __expf(r[7] - mx);
  }
  #pragma unroll
  for (int d = 4; d > 0; d >>= 1) se += __shfl_xor(se, d, 8);
  if (lead) {
    const float lse = mx + logf(se);
    float4 o0, o1;
    o0.x = r[0] - lse; o0.y = r[1] - lse; o0.z = r[2] - lse; o0.w = r[3] - lse;
    o1.x = r[4] - lse; o1.y = r[5] - lse; o1.z = r[6] - lse; o1.w = r[7] - lse;
    ((float4*)out)[node * 10 + lane * 2] = o0;
    ((float4*)out)[node * 10 + lane * 2 + 1] = o1;
  }
}

// ---------------- launch ----------------

extern "C" void kernel_launch(void* const* d_in, const int* in_sizes, int n_in,
                              void* d_out, int out_size, void* d_ws, size_t ws_size,
                              hipStream_t stream) {
  const float* x   = (const float*)d_in[0];
  const int*   ei  = (const int*)d_in[1];   // [2][NE], int32
  const float* W1  = (const float*)d_in[3];
  const float* b1  = (const float*)d_in[4];
  const float* W2  = (const float*)d_in[5];
  const float* b2  = (const float*)d_in[6];
  float*       out = (float*)d_out;

  char* ws = (char*)d_ws;
  int*      tail    = (int*)(ws + 0);                            // NBUK ints
  int*      bstart  = (int*)(ws + (size_t)4 * 1024);             // NBUK+1 ints
  int*      offsets = (int*)(ws + (size_t)8 * 1024);             // (NN+1)*4 = 400KB
  float*    dinv    = (float*)(ws + (size_t)512 * 1024);         // NN*4 = 400KB
  int*      csr_src = (int*)(ws + (size_t)1024 * 1024);          // NE*4 = 12.8MB
  unsigned* bucket  = (unsigned*)(ws + (size_t)14 * 1024 * 1024);// 13.6MB, dead after k_sort
  unsigned* m1b     = (unsigned*)(ws + (size_t)14 * 1024 * 1024);// 12.8MB bf16 (overlays bucket)
  float*    a1      = (float*)(ws + (size_t)40 * 1024 * 1024);   // 25.6MB fp32
  unsigned* m2b     = m1b;  // m1b dead after agg1 (NN*20*4 = 8MB)

  k_zero<<<2, 256, 0, stream>>>(tail, NBUK);
  k_bucket<<<(NE + EPB - 1) / EPB, 256, 0, stream>>>(ei, tail, bucket);
  k_bstart<<<1, 512, 0, stream>>>(tail, bstart);
  k_sort<<<NBUK, 256, 0, stream>>>(bucket, tail, bstart, csr_src, offsets, dinv);
  k_gemm1<<<(NN + 127) / 128, 128, 0, stream>>>(x, W1, dinv, m1b);
  k_agg1<<<NN / 4, 256, 0, stream>>>(m1b, offsets, csr_src, dinv, b1, a1);
  k_gemm2<<<(NN * 20 + 255) / 256, 256, 0, stream>>>(a1, W2, dinv, m2b);
  k_agg2<<<NN / 4, 256, 0, stream>>>(m2b, offsets, csr_src, dinv, b2, out);
}

// Round 6
// 221.349 us; speedup vs baseline: 1.0726x; 1.0531x over previous
//
#include <hip/hip_runtime.h>
#include <math.h>

// GCN 2-layer forward on MI355X.
// Lessons r2-r6: (a) random 4B global stores => ~130MB writebacks however
// sharded; (b) coarse buckets => 32x re-read in pass 2; (c) LDS-accumulator
// aggregation is latency-serial (1404us); (d) wave-per-node CSR gather agg
// is fast (<=129us, r3/r4). One-pass fine bucket partition -> per-bucket
// LDS counting sort -> CSR gather aggs; log_softmax fused into agg2.
// r7/r8: wide masked row-gathers; agg pinned at 3.8 TB/s L2-miss rate =>
// byte-ceilinged. r9: m1/m2 stored bf16 -> agg bytes halved; total 338->236.
// r10 FAILED: broadcast remap didn't cut LDS return bytes (broadcast b128
// still costs full 1KB return; model matched 70us measured).
// r11 FAILED: 8x8 tile cut bytes/FMA 5x but 128-thr x 41.5KB blocks = 6
// waves/CU -> latency-starved (VALU 18%, occ 10.6%).
// r12: joint fix: 4x8 tile, 256-thr blocks, 128 rows/block (782 blocks,
// balanced 3.05/CU), LDS 40.25KB -> 3 blk/CU = 12 waves/CU. Per kk: 3
// b128 per 32 FMA (96B/FMA): LDS ~17us vs FMA 10.4us, overlapped.

#define NN 100000
#define NE 3200000
#define NBUK 391            // ceil(NN/256); bucket b covers cols [b*256 ...)
#define BCAP 8704           // mean 8184, sd ~90; +5.7 sigma slack
#define EPB 16384           // edges per k_bucket block -> 196 blocks

// ---------------- zero (tail) ----------------

__global__ void k_zero(int* __restrict__ p, int n) {
  int i = blockIdx.x * blockDim.x + threadIdx.x;
  if (i < n) p[i] = 0;
}

// ---------------- bf16 helpers ----------------

__device__ __forceinline__ unsigned bf16rne(float x) {
  unsigned u = __float_as_uint(x);
  return (u + 0x7fffu + ((u >> 16) & 1u)) >> 16;
}
__device__ __forceinline__ unsigned pack2(float lo, float hi) {
  return bf16rne(lo) | (bf16rne(hi) << 16);
}

// ---------------- one-pass 391-way bucket partition ----------------

__global__ __launch_bounds__(256) void k_bucket(const int* __restrict__ ei,
                                                int* __restrict__ tail,
                                                unsigned* __restrict__ bucket) {
  __shared__ int hist[NBUK], wbase[NBUK], loc[NBUK];
  const int tid = threadIdx.x;
  const int beg = blockIdx.x * EPB;
  const int end = min(beg + EPB, NE);
  const int* col = ei + NE;
  for (int b = tid; b < NBUK; b += 256) { hist[b] = 0; loc[b] = 0; }
  __syncthreads();
  for (int e = beg + tid * 4; e < end; e += 1024) {
    int4 c4 = *(const int4*)(col + e);
    atomicAdd(&hist[c4.x >> 8], 1);
    atomicAdd(&hist[c4.y >> 8], 1);
    atomicAdd(&hist[c4.z >> 8], 1);
    atomicAdd(&hist[c4.w >> 8], 1);
  }
  __syncthreads();
  for (int b = tid; b < NBUK; b += 256)
    wbase[b] = atomicAdd(&tail[b], hist[b]);   // contiguous block-private run
  __syncthreads();
  for (int e = beg + tid * 4; e < end; e += 1024) {
    int4 c4 = *(const int4*)(col + e);         // L2-hot re-read
    int4 r4 = *(const int4*)(ei + e);
    {
      int b = c4.x >> 8;
      unsigned pos = (unsigned)(wbase[b] + atomicAdd(&loc[b], 1));
      if (pos < BCAP) bucket[(size_t)b * BCAP + pos] = ((unsigned)r4.x << 8) | (unsigned)(c4.x & 255);
    }
    {
      int b = c4.y >> 8;
      unsigned pos = (unsigned)(wbase[b] + atomicAdd(&loc[b], 1));
      if (pos < BCAP) bucket[(size_t)b * BCAP + pos] = ((unsigned)r4.y << 8) | (unsigned)(c4.y & 255);
    }
    {
      int b = c4.z >> 8;
      unsigned pos = (unsigned)(wbase[b] + atomicAdd(&loc[b], 1));
      if (pos < BCAP) bucket[(size_t)b * BCAP + pos] = ((unsigned)r4.z << 8) | (unsigned)(c4.z & 255);
    }
    {
      int b = c4.w >> 8;
      unsigned pos = (unsigned)(wbase[b] + atomicAdd(&loc[b], 1));
      if (pos < BCAP) bucket[(size_t)b * BCAP + pos] = ((unsigned)r4.w << 8) | (unsigned)(c4.w & 255);
    }
  }
}

// ---------------- bucket-start prefix sum (391 elems, 1 block) ----------------

__global__ void k_bstart(const int* __restrict__ tail, int* __restrict__ bstart) {
  const int tid = threadIdx.x, lane = tid & 63, wid = tid >> 6;   // 512 thr
  int v = (tid < NBUK) ? min(tail[tid], BCAP) : 0;
  int s = v;
  #pragma unroll
  for (int d = 1; d < 64; d <<= 1) { int t = __shfl_up(s, d, 64); if (lane >= d) s += t; }
  __shared__ int wsum[8];
  if (lane == 63) wsum[wid] = s;
  __syncthreads();
  int wpre = 0;
  for (int w = 0; w < wid; ++w) wpre += wsum[w];
  int excl = wpre + s - v;
  if (tid <= NBUK) bstart[tid] = excl;     // bstart[NBUK] = total
}

// ---------------- per-bucket LDS counting sort -> CSR + offsets + dinv ----------------

__global__ __launch_bounds__(256) void k_sort(const unsigned* __restrict__ bucket,
                                              const int* __restrict__ tail,
                                              const int* __restrict__ bstart,
                                              int* __restrict__ csr_src,
                                              int* __restrict__ offsets,
                                              float* __restrict__ dinv) {
  __shared__ int h[256], base_[256], loc[256];
  __shared__ int sorted[BCAP];              // 34.8 KB
  __shared__ int wsum[4];
  const int b = blockIdx.x;
  const int lo = b << 8;
  const int nc = min(256, NN - lo);
  const int n = min(tail[b], BCAP);
  const int seg0 = bstart[b];
  const unsigned* __restrict__ bk = bucket + (size_t)b * BCAP;
  const int tid = threadIdx.x, lane = tid & 63, wid = tid >> 6;
  h[tid] = 0; loc[tid] = 0;
  __syncthreads();
  int i = tid * 4;
  for (; i + 3 < n; i += 1024) {
    uint4 v = *(const uint4*)(bk + i);
    atomicAdd(&h[v.x & 255u], 1);
    atomicAdd(&h[v.y & 255u], 1);
    atomicAdd(&h[v.z & 255u], 1);
    atomicAdd(&h[v.w & 255u], 1);
  }
  for (; i < n; ++i) atomicAdd(&h[bk[i] & 255u], 1);
  __syncthreads();
  {  // exclusive scan of h[0..255]
    int v = h[tid];
    int s = v;
    #pragma unroll
    for (int d = 1; d < 64; d <<= 1) { int t = __shfl_up(s, d, 64); if (lane >= d) s += t; }
    if (lane == 63) wsum[wid] = s;
    __syncthreads();
    int wpre = 0;
    #pragma unroll
    for (int w = 0; w < 4; ++w) if (w < wid) wpre += wsum[w];
    int excl = wpre + s - v;
    base_[tid] = excl;
    if (tid < nc) {
      dinv[lo + tid] = rsqrtf((float)(v + 1));       // +1 = self-loop
      offsets[lo + tid] = seg0 + excl;
    }
  }
  if (b == 0 && tid == 0) offsets[NN] = bstart[NBUK];
  __syncthreads();
  i = tid * 4;
  for (; i + 3 < n; i += 1024) {
    uint4 v = *(const uint4*)(bk + i);
    { int c = v.x & 255u; sorted[base_[c] + atomicAdd(&loc[c], 1)] = (int)(v.x >> 8); }
    { int c = v.y & 255u; sorted[base_[c] + atomicAdd(&loc[c], 1)] = (int)(v.y >> 8); }
    { int c = v.z & 255u; sorted[base_[c] + atomicAdd(&loc[c], 1)] = (int)(v.z >> 8); }
    { int c = v.w & 255u; sorted[base_[c] + atomicAdd(&loc[c], 1)] = (int)(v.w >> 8); }
  }
  for (; i < n; ++i) {
    unsigned ent = bk[i];
    int c = ent & 255u;
    sorted[base_[c] + atomicAdd(&loc[c], 1)] = (int)(ent >> 8);
  }
  __syncthreads();
  for (int t = tid; t < n; t += 256) csr_src[seg0 + t] = sorted[t];   // coalesced
}

// ---------------- layer 1 GEMM: m1b = bf16(dinv * (x @ W1)), 128 -> 64 --------
// 4x8 register tile. cg = tid&7 -> ch 8cg..8cg+7; rg = tid>>3 (0..31) ->
// rows 4rg..4rg+3. xt staged transposed per 16-k slice [k][row pad 132];
// ws fp32 [k][64]. Per kk: 1 xt b128 (8 distinct addrs, conflict-free) +
// 2 ws b128 (2-way) = 3KB wave-return per 32 wave-FMA. 40.25KB LDS ->
// 3 blocks/CU = 12 waves/CU.

__global__ __launch_bounds__(256) void k_gemm1(const float* __restrict__ x,
                                               const float* __restrict__ W1,
                                               const float* __restrict__ dinv,
                                               unsigned* __restrict__ m1b) {
  __shared__ float ws[128 * 64];      // 32 KB, [k][c]
  __shared__ float xt[16 * 132];      // 8.25 KB, [k in slice][row pad 132]
  const int tid = threadIdx.x;
  const int row0 = blockIdx.x * 128;  // 782 blocks
  {
    const float4* __restrict__ w4 = (const float4*)W1;
    float4* __restrict__ s4 = (float4*)ws;
    for (int i = tid; i < 128 * 16; i += 256) s4[i] = w4[i];
  }
  const int cg = tid & 7;             // channels 8cg..8cg+7
  const int rg = tid >> 3;            // 0..31 -> rows 4rg..4rg+3
  const int srow = tid & 127;         // staging row
  const int skh = tid >> 7;           // staging k-octet (0/1)
  float acc[4][8];
  #pragma unroll
  for (int i = 0; i < 4; ++i)
    #pragma unroll
    for (int j = 0; j < 8; ++j) acc[i][j] = 0.f;
  const float4* __restrict__ xt4 = (const float4*)xt;
  const float4* __restrict__ ws4 = (const float4*)ws;
  for (int ks = 0; ks < 8; ++ks) {
    __syncthreads();
    {   // stage 128 rows x 16 k, transposed; loads 16B granules, L2-hot
      int grow = row0 + srow; if (grow > NN - 1) grow = NN - 1;
      const float* xp = x + (size_t)grow * 128 + ks * 16 + skh * 8;
      float4 va = *(const float4*)xp;
      float4 vb = *(const float4*)(xp + 4);
      const int kb = skh * 8;
      xt[(kb + 0) * 132 + srow] = va.x;
      xt[(kb + 1) * 132 + srow] = va.y;
      xt[(kb + 2) * 132 + srow] = va.z;
      xt[(kb + 3) * 132 + srow] = va.w;
      xt[(kb + 4) * 132 + srow] = vb.x;
      xt[(kb + 5) * 132 + srow] = vb.y;
      xt[(kb + 6) * 132 + srow] = vb.z;
      xt[(kb + 7) * 132 + srow] = vb.w;
    }
    __syncthreads();
    #pragma unroll 4
    for (int kk = 0; kk < 16; ++kk) {
      const int k = ks * 16 + kk;
      float4 xv = xt4[kk * 33 + rg];
      float4 wa = ws4[k * 16 + cg * 2];
      float4 wb = ws4[k * 16 + cg * 2 + 1];
      float xr[4] = {xv.x, xv.y, xv.z, xv.w};
      float wc[8] = {wa.x, wa.y, wa.z, wa.w, wb.x, wb.y, wb.z, wb.w};
      #pragma unroll
      for (int i = 0; i < 4; ++i)
        #pragma unroll
        for (int j = 0; j < 8; ++j)
          acc[i][j] = fmaf(xr[i], wc[j], acc[i][j]);
    }
  }
  #pragma unroll
  for (int i = 0; i < 4; ++i) {
    const int row = row0 + rg * 4 + i;
    if (row < NN) {
      const float d = dinv[row];
      uint4 o;
      o.x = pack2(acc[i][0] * d, acc[i][1] * d);
      o.y = pack2(acc[i][2] * d, acc[i][3] * d);
      o.z = pack2(acc[i][4] * d, acc[i][5] * d);
      o.w = pack2(acc[i][6] * d, acc[i][7] * d);
      ((uint4*)m1b)[row * 8 + cg] = o;   // ch 8cg..8cg+7 = u32 slots 4cg..4cg+3
    }
  }
}

// ---------------- unpack-accumulate: uint4 = 8 bf16 channels ----------------

#define ACC8(v, f)                                                   \
  acc[0] = fmaf(__uint_as_float((v).x << 16), (f), acc[0]);          \
  acc[1] = fmaf(__uint_as_float((v).x & 0xffff0000u), (f), acc[1]);  \
  acc[2] = fmaf(__uint_as_float((v).y << 16), (f), acc[2]);          \
  acc[3] = fmaf(__uint_as_float((v).y & 0xffff0000u), (f), acc[3]);  \
  acc[4] = fmaf(__uint_as_float((v).z << 16), (f), acc[4]);          \
  acc[5] = fmaf(__uint_as_float((v).z & 0xffff0000u), (f), acc[5]);  \
  acc[6] = fmaf(__uint_as_float((v).w << 16), (f), acc[6]);          \
  acc[7] = fmaf(__uint_as_float((v).w & 0xffff0000u), (f), acc[7]);

// ---------------- layer 1 aggregation (bf16 rows, 8 rows/instr) -------------
// Lane layout: e = lane>>3 (edge slot 0..7), q = lane&7 (16B chunk = 8 ch).
// Chunk = 32 edges via 4 dwordx4 gathers (8 rows each). Invalid slots clamp
// index to beg and contribute via fma x0.0. fp32 accumulate.

__global__ __launch_bounds__(256) void k_agg1(const unsigned* __restrict__ m1b,
                                              const int* __restrict__ offsets,
                                              const int* __restrict__ csr_src,
                                              const float* __restrict__ dinv,
                                              const float* __restrict__ b1,
                                              float* __restrict__ a1) {
  const int node = blockIdx.x * 4 + (threadIdx.x >> 6);
  const int lane = threadIdx.x & 63;
  const int e = lane >> 3;
  const int q = lane & 7;
  const uint4* __restrict__ m1v = (const uint4*)m1b;
  const int beg = offsets[node], end = offsets[node + 1];
  float acc[8];
  #pragma unroll
  for (int j = 0; j < 8; ++j) acc[j] = 0.f;
  for (int p = beg; p < end; p += 32) {
    const int i0 = p + e, i1 = p + 8 + e, i2 = p + 16 + e, i3 = p + 24 + e;
    const int s0 = csr_src[i0 < end ? i0 : beg];
    const int s1 = csr_src[i1 < end ? i1 : beg];
    const int s2 = csr_src[i2 < end ? i2 : beg];
    const int s3 = csr_src[i3 < end ? i3 : beg];
    const float f0 = (i0 < end) ? 1.f : 0.f;
    const float f1 = (i1 < end) ? 1.f : 0.f;
    const float f2 = (i2 < end) ? 1.f : 0.f;
    const float f3 = (i3 < end) ? 1.f : 0.f;
    uint4 v0 = m1v[s0 * 8 + q];
    uint4 v1 = m1v[s1 * 8 + q];
    uint4 v2 = m1v[s2 * 8 + q];
    uint4 v3 = m1v[s3 * 8 + q];
    ACC8(v0, f0);
    ACC8(v1, f1);
    ACC8(v2, f2);
    ACC8(v3, f3);
  }
  // reduce the 8 edge slots; channel chunk q stays put
  #pragma unroll
  for (int j = 0; j < 8; ++j) {
    acc[j] += __shfl_xor(acc[j], 8, 64);
    acc[j] += __shfl_xor(acc[j], 16, 64);
    acc[j] += __shfl_xor(acc[j], 32, 64);
  }
  if (e == 0) {                       // lanes 0..7 hold chunk q = lane
    uint4 sv = m1v[node * 8 + q];     // self-loop row
    const float d = dinv[node];
    float4 bb0 = ((const float4*)b1)[q * 2];
    float4 bb1 = ((const float4*)b1)[q * 2 + 1];
    float4 o0, o1;
    o0.x = (acc[0] + __uint_as_float(sv.x << 16)) * d + bb0.x;
    o0.y = (acc[1] + __uint_as_float(sv.x & 0xffff0000u)) * d + bb0.y;
    o0.z = (acc[2] + __uint_as_float(sv.y << 16)) * d + bb0.z;
    o0.w = (acc[3] + __uint_as_float(sv.y & 0xffff0000u)) * d + bb0.w;
    o1.x = (acc[4] + __uint_as_float(sv.z << 16)) * d + bb1.x;
    o1.y = (acc[5] + __uint_as_float(sv.z & 0xffff0000u)) * d + bb1.y;
    o1.z = (acc[6] + __uint_as_float(sv.w << 16)) * d + bb1.z;
    o1.w = (acc[7] + __uint_as_float(sv.w & 0xffff0000u)) * d + bb1.w;
    ((float4*)a1)[node * 16 + q * 2] = o0;
    ((float4*)a1)[node * 16 + q * 2 + 1] = o1;
  }
}

// ---------------- layer 2 GEMM: m2b = bf16(dinv * (a1 @ W2)), 64 -> 40 ------

__global__ __launch_bounds__(256) void k_gemm2(const float* __restrict__ a1,
                                               const float* __restrict__ W2,
                                               const float* __restrict__ dinv,
                                               unsigned* __restrict__ m2b) {
  __shared__ float ws[64 * 40];    // 10 KB
  const int tid = threadIdx.x;
  for (int k = tid; k < 64 * 40; k += 256) ws[k] = W2[k];
  __syncthreads();
  const int idx = blockIdx.x * 256 + tid;                // thread = (node, ch-pair)
  if (idx >= NN * 20) return;
  const int node = idx / 20;
  const int c0 = (idx - node * 20) * 2;
  const float4* __restrict__ a4 = (const float4*)(a1 + node * 64);
  float acc0 = 0.f, acc1 = 0.f;
  #pragma unroll
  for (int k4 = 0; k4 < 16; ++k4) {
    float4 a = a4[k4];
    acc0 = fmaf(a.x, ws[(k4 * 4 + 0) * 40 + c0], acc0);
    acc1 = fmaf(a.x, ws[(k4 * 4 + 0) * 40 + c0 + 1], acc1);
    acc0 = fmaf(a.y, ws[(k4 * 4 + 1) * 40 + c0], acc0);
    acc1 = fmaf(a.y, ws[(k4 * 4 + 1) * 40 + c0 + 1], acc1);
    acc0 = fmaf(a.z, ws[(k4 * 4 + 2) * 40 + c0], acc0);
    acc1 = fmaf(a.z, ws[(k4 * 4 + 2) * 40 + c0 + 1], acc1);
    acc0 = fmaf(a.w, ws[(k4 * 4 + 3) * 40 + c0], acc0);
    acc1 = fmaf(a.w, ws[(k4 * 4 + 3) * 40 + c0 + 1], acc1);
  }
  const float d = dinv[node];
  m2b[idx] = pack2(acc0 * d, acc1 * d);
}

// ---------------- layer 2 aggregation + bias + log_softmax ------------------
// Lane layout: e = lane/5 (edge slot 0..11), q = lane%5 (16B chunk = 8 ch);
// lanes 60..63 masked (f=0). Chunk = 48 edges via 4 dwordx4 gathers (12
// rows each). Reduce 12 slots via shfl (+30, +15, +5/+10); log_softmax
// over 5 lanes x 8 comps via width-8 xor (lanes 5..7 seeded -inf/0).

__device__ __forceinline__ float shfl1(float v, int src) {
  return __shfl(v, src & 63, 64);
}

__global__ __launch_bounds__(256) void k_agg2(const unsigned* __restrict__ m2b,
                                              const int* __restrict__ offsets,
                                              const int* __restrict__ csr_src,
                                              const float* __restrict__ dinv,
                                              const float* __restrict__ b2,
                                              float* __restrict__ out) {
  const int node = blockIdx.x * 4 + (threadIdx.x >> 6);
  const int lane = threadIdx.x & 63;
  const bool act = lane < 60;
  const int e = act ? (lane / 5) : 0;
  const int q = act ? (lane - e * 5) : 0;
  const uint4* __restrict__ m2v = (const uint4*)m2b;
  const int beg = offsets[node], end = offsets[node + 1];
  float acc[8];
  #pragma unroll
  for (int j = 0; j < 8; ++j) acc[j] = 0.f;
  for (int p = beg; p < end; p += 48) {
    const int i0 = p + e, i1 = p + 12 + e, i2 = p + 24 + e, i3 = p + 36 + e;
    const int s0 = csr_src[i0 < end ? i0 : beg];
    const int s1 = csr_src[i1 < end ? i1 : beg];
    const int s2 = csr_src[i2 < end ? i2 : beg];
    const int s3 = csr_src[i3 < end ? i3 : beg];
    const float f0 = (act && i0 < end) ? 1.f : 0.f;
    const float f1 = (act && i1 < end) ? 1.f : 0.f;
    const float f2 = (act && i2 < end) ? 1.f : 0.f;
    const float f3 = (act && i3 < end) ? 1.f : 0.f;
    uint4 v0 = m2v[s0 * 5 + q];
    uint4 v1 = m2v[s1 * 5 + q];
    uint4 v2 = m2v[s2 * 5 + q];
    uint4 v3 = m2v[s3 * 5 + q];
    ACC8(v0, f0);
    ACC8(v1, f1);
    ACC8(v2, f2);
    ACC8(v3, f3);
  }
  // reduce 12 slots: lanes 0..29 += lanes+30; lanes 0..14 += lanes+15;
  // lanes 0..4 += lanes+5 and lanes+10
  #pragma unroll
  for (int j = 0; j < 8; ++j) acc[j] += shfl1(acc[j], lane + 30);
  #pragma unroll
  for (int j = 0; j < 8; ++j) acc[j] += shfl1(acc[j], lane + 15);
  #pragma unroll
  for (int j = 0; j < 8; ++j) {
    float t1 = shfl1(acc[j], lane + 5);
    float t2 = shfl1(acc[j], lane + 10);
    acc[j] += t1 + t2;
  }
  const bool lead = (lane < 5);
  float r[8];
  #pragma unroll
  for (int j = 0; j < 8; ++j) r[j] = 0.f;
  if (lead) {
    uint4 sv = m2v[node * 5 + lane];   // self-loop row (q == lane here)
    const float d = dinv[node];
    float4 bb0 = ((const float4*)b2)[lane * 2];
    float4 bb1 = ((const float4*)b2)[lane * 2 + 1];
    r[0] = (acc[0] + __uint_as_float(sv.x << 16)) * d + bb0.x;
    r[1] = (acc[1] + __uint_as_float(sv.x & 0xffff0000u)) * d + bb0.y;
    r[2] = (acc[2] + __uint_as_float(sv.y << 16)) * d + bb0.z;
    r[3] = (acc[3] + __uint_as_float(sv.y & 0xffff0000u)) * d + bb0.w;
    r[4] = (acc[4] + __uint_as_float(sv.z << 16)) * d + bb1.x;
    r[5] = (acc[5] + __uint_as_float(sv.z & 0xffff0000u)) * d + bb1.y;
    r[6] = (acc[6] + __uint_as_float(sv.w << 16)) * d + bb1.z;
    r[7] = (acc[7] + __uint_as_float(sv.w & 0xffff0000u)) * d + bb1.w;
  }
  // log_softmax over 40 = 5 lanes x 8 comps (width-8 xor; lanes 5..7 seeded)
  float mx = -INFINITY;
  if (lead) {
    mx = fmaxf(fmaxf(fmaxf(r[0], r[1]), fmaxf(r[2], r[3])),
               fmaxf(fmaxf(r[4], r[5]), fmaxf(r[6], r[7])));
  }
  #pragma unroll
  for (int d = 4; d > 0; d >>= 1) mx = fmaxf(mx, __shfl_xor(mx, d, 8));
  float se = 0.f;
  if (lead) {
    se = __expf(r[0] - mx) + __expf(r[1] - mx) + __expf(r[2] - mx) +
         __expf(r[3] - mx) + __expf(r[4] - mx) + __expf(r[5] - mx) +
         __expf(r[6] - mx) + __expf(r[7] - mx);
  }
  #pragma unroll
  for (int d = 4; d > 0; d >>= 1) se += __shfl_xor(se, d, 8);
  if (lead) {
    const float lse = mx + logf(se);
    float4 o0, o1;
    o0.x = r[0] - lse; o0.y = r[1] - lse; o0.z = r[2] - lse; o0.w = r[3] - lse;
    o1.x = r[4] - lse; o1.y = r[5] - lse; o1.z = r[6] - lse; o1.w = r[7] - lse;
    ((float4*)out)[node * 10 + lane * 2] = o0;
    ((float4*)out)[node * 10 + lane * 2 + 1] = o1;
  }
}

// ---------------- launch ----------------

extern "C" void kernel_launch(void* const* d_in, const int* in_sizes, int n_in,
                              void* d_out, int out_size, void* d_ws, size_t ws_size,
                              hipStream_t stream) {
  const float* x   = (const float*)d_in[0];
  const int*   ei  = (const int*)d_in[1];   // [2][NE], int32
  const float* W1  = (const float*)d_in[3];
  const float* b1  = (const float*)d_in[4];
  const float* W2  = (const float*)d_in[5];
  const float* b2  = (const float*)d_in[6];
  float*       out = (float*)d_out;

  char* ws = (char*)d_ws;
  int*      tail    = (int*)(ws + 0);                            // NBUK ints
  int*      bstart  = (int*)(ws + (size_t)4 * 1024);             // NBUK+1 ints
  int*      offsets = (int*)(ws + (size_t)8 * 1024);             // (NN+1)*4 = 400KB
  float*    dinv    = (float*)(ws + (size_t)512 * 1024);         // NN*4 = 400KB
  int*      csr_src = (int*)(ws + (size_t)1024 * 1024);          // NE*4 = 12.8MB
  unsigned* bucket  = (unsigned*)(ws + (size_t)14 * 1024 * 1024);// 13.6MB, dead after k_sort
  unsigned* m1b     = (unsigned*)(ws + (size_t)14 * 1024 * 1024);// 12.8MB bf16 (overlays bucket)
  float*    a1      = (float*)(ws + (size_t)40 * 1024 * 1024);   // 25.6MB fp32
  unsigned* m2b     = m1b;  // m1b dead after agg1 (NN*20*4 = 8MB)

  k_zero<<<2, 256, 0, stream>>>(tail, NBUK);
  k_bucket<<<(NE + EPB - 1) / EPB, 256, 0, stream>>>(ei, tail, bucket);
  k_bstart<<<1, 512, 0, stream>>>(tail, bstart);
  k_sort<<<NBUK, 256, 0, stream>>>(bucket, tail, bstart, csr_src, offsets, dinv);
  k_gemm1<<<(NN + 127) / 128, 256, 0, stream>>>(x, W1, dinv, m1b);
  k_agg1<<<NN / 4, 256, 0, stream>>>(m1b, offsets, csr_src, dinv, b1, a1);
  k_gemm2<<<(NN * 20 + 255) / 256, 256, 0, stream>>>(a1, W2, dinv, m2b);
  k_agg2<<<NN / 4, 256, 0, stream>>>(m2b, offsets, csr_src, dinv, b2, out);
}